// Round 4
// baseline (227.196 us; speedup 1.0000x reference)
//
#include <hip/hip_runtime.h>

typedef __attribute__((ext_vector_type(2))) float f32x2;

#define W 4096
#define H 4096
#define NT 256
#define COLS 512                 // columns per block (2 per thread)
#define SR 32                    // output rows per block strip
#define GROUP 4                  // rows staged per barrier
#define NSTAGE (SR + 14)         // 46 rows contribute
#define NG 12                    // 12 groups of 4 (48 slots, last 2 unused)
#define LW (COLS + 16)           // 528 floats per staged row (8-col halo each side)
#define NCHUNK (LW / 4)          // 132 float4 chunks per row
#define RAD 7

__global__ __launch_bounds__(NT, 4) void multibox_kernel(
    const float* __restrict__ x, const float* __restrict__ base,
    float* __restrict__ out)
{
    __shared__ float buf[2][GROUP][LW];   // 16,896 B

    const int t  = threadIdx.x;
    const int c0 = blockIdx.x * COLS;
    const int i0 = blockIdx.y * SR;

    const float w3  = 1.f/(7.f*9.f);
    const float w5  = 1.f/(7.f*25.f);
    const float w7  = 1.f/(7.f*49.f);
    const float w9  = 1.f/(7.f*81.f);
    const float w11 = 1.f/(7.f*121.f);
    const float w13 = 1.f/(7.f*169.f);
    const float w15 = 1.f/(7.f*225.f);

    auto ld4 = [&](const float* __restrict__ rowp, int c) -> float4 {
        if (c >= 0 && c <= W - 4) return *(const float4*)(rowp + c);
        float4 v;
        v.x = rowp[min(max(c    , 0), W - 1)];
        v.y = rowp[min(max(c + 1, 0), W - 1)];
        v.z = rowp[min(max(c + 2, 0), W - 1)];
        v.w = rowp[min(max(c + 3, 0), W - 1)];
        return v;
    };

    float4 mreg[GROUP];

    auto load_group = [&](int g) {
        if (t < NCHUNK) {
            const int rb = i0 - RAD + g * GROUP;
#pragma unroll
            for (int rr = 0; rr < GROUP; ++rr) {
                const int rc = min(max(rb + rr, 0), H - 1);
                mreg[rr] = ld4(x + (size_t)rc * W, c0 - 8 + 4 * t);
            }
        }
    };

    auto write_group = [&](int b) {
        if (t < NCHUNK) {
#pragma unroll
            for (int rr = 0; rr < GROUP; ++rr)
                *(float4*)&buf[b][rr][4 * t] = mreg[rr];
        }
    };

    // rotating pending accumulators: while processing staged row idx, logical
    // pend[q] lives at Pnd[(idx + q) % 15]. The slot ENTERING the window
    // (q = 14) is ASSIGNED, not accumulated -> each 15-step window starts
    // clean with no explicit reset (fixes round-3 warm-up contamination).
    f32x2 Pnd[15];
#pragma unroll
    for (int q = 0; q < 15; ++q) Pnd[q] = f32x2{0.f, 0.f};

    auto compute_group = [&](int b, int g) {
#pragma unroll
        for (int rr = 0; rr < GROUP; ++rr) {
            const int idx = g * GROUP + rr;          // compile-time after unroll
            if (idx >= NSTAGE) continue;

            // q2[i] = row floats {2t+2i, 2t+2i+1}; covers [2t, 2t+17]
            const float* p = &buf[b][rr][2 * t];
            f32x2 q2[9];
#pragma unroll
            for (int i = 0; i < 9; ++i) q2[i] = *(const f32x2*)(p + 2 * i);

            // PR(a) = {row[2t+a], row[2t+a+1]},  a = 1..15 (compile-time)
            auto PR = [&](int a) -> f32x2 {
                if ((a & 1) == 0) return q2[a / 2];
                f32x2 r;
                r.x = q2[a / 2].y;
                r.y = q2[a / 2 + 1].x;
                return r;
            };

            // horizontal ring sums for the column pair (2t, 2t+1)
            f32x2 s3  = PR(7) + PR(8) + PR(9);
            f32x2 s5  = s3  + PR(6) + PR(10);
            f32x2 s7  = s5  + PR(5) + PR(11);
            f32x2 s9  = s7  + PR(4) + PR(12);
            f32x2 s11 = s9  + PR(3) + PR(13);
            f32x2 s13 = s11 + PR(2) + PR(14);
            f32x2 s15 = s13 + PR(1) + PR(15);

            // suffix sums (fma chain)
            f32x2 c7 = f32x2{w15, w15} * s15;
            f32x2 c6 = c7 + f32x2{w13, w13} * s13;
            f32x2 c5 = c6 + f32x2{w11, w11} * s11;
            f32x2 c4 = c5 + f32x2{w9 , w9 } * s9;
            f32x2 c3 = c4 + f32x2{w7 , w7 } * s7;
            f32x2 c2 = c3 + f32x2{w5 , w5 } * s5;
            f32x2 c1 = c2 + f32x2{w3 , w3 } * s3;

            // scatter: Pnd[(idx+q)%15] += cum[|q-7|]; entering slot ASSIGNED
            Pnd[(idx +  0) % 15] += c7;
            Pnd[(idx +  1) % 15] += c6;
            Pnd[(idx +  2) % 15] += c5;
            Pnd[(idx +  3) % 15] += c4;
            Pnd[(idx +  4) % 15] += c3;
            Pnd[(idx +  5) % 15] += c2;
            Pnd[(idx +  6) % 15] += c1;
            Pnd[(idx +  7) % 15] += c1;
            Pnd[(idx +  8) % 15] += c1;
            Pnd[(idx +  9) % 15] += c2;
            Pnd[(idx + 10) % 15] += c3;
            Pnd[(idx + 11) % 15] += c4;
            Pnd[(idx + 12) % 15] += c5;
            Pnd[(idx + 13) % 15] += c6;
            Pnd[(idx + 14) % 15] =  c7;   // entering slot: overwrite, not +=

            // staged row idx completes output row o = i0 + idx - 14
            if (idx >= 14) {
                const int o = i0 + idx - 14;
                const size_t bi = (size_t)o * W + c0 + 2 * t;
                f32x2 bm = *(const f32x2*)(base + bi);
                f32x2 ov = Pnd[idx % 15] * bm;
                *(f32x2*)(out + bi) = ov;
                // no reset needed: this slot re-enters next step via assignment
            }
        }
    };

    load_group(0);
    write_group(0);
    __syncthreads();

#pragma unroll
    for (int g = 0; g < NG - 1; ++g) {
        load_group(g + 1);           // issue next group's global loads early
        compute_group(g & 1, g);     // compute current group (hides latency)
        write_group((g + 1) & 1);    // land prefetched rows
        __syncthreads();
    }
    compute_group((NG - 1) & 1, NG - 1);
}

extern "C" void kernel_launch(void* const* d_in, const int* in_sizes, int n_in,
                              void* d_out, int out_size, void* d_ws, size_t ws_size,
                              hipStream_t stream) {
    const float* x    = (const float*)d_in[0];
    const float* base = (const float*)d_in[1];
    float* out        = (float*)d_out;

    dim3 grid(W / COLS, H / SR);   // (8, 128) = 1024 blocks
    multibox_kernel<<<grid, dim3(NT), 0, stream>>>(x, base, out);
}

// Round 5
// 60.912 us; speedup vs baseline: 3.7299x; 3.7299x over previous
//
#include <hip/hip_runtime.h>

typedef __attribute__((ext_vector_type(2))) float f32x2;

#define W 4096
#define H 4096
#define NT 256
#define COLS 512                 // columns per block (2 per thread)
#define SR 32                    // output rows per block strip
#define GROUP 4                  // rows staged per barrier
#define NSTAGE (SR + 14)         // 46 staged rows contribute
#define NG 12                    // 12 groups of 4 (48 slots, last 2 guarded off)
#define LW (COLS + 16)           // 528 floats per staged row (8-col halo each side)
#define NCHUNK (LW / 4)          // 132 float4 chunks per row
#define RAD 7
#define PEND 18                  // 15 + GROUP - 1

__global__ __launch_bounds__(NT, 4) void multibox_kernel(
    const float* __restrict__ x, const float* __restrict__ base,
    float* __restrict__ out)
{
    __shared__ float buf[2][GROUP][LW];   // 16,896 B

    const int t  = threadIdx.x;
    const int c0 = blockIdx.x * COLS;
    const int i0 = blockIdx.y * SR;

    const float w3  = 1.f/(7.f*9.f);
    const float w5  = 1.f/(7.f*25.f);
    const float w7  = 1.f/(7.f*49.f);
    const float w9  = 1.f/(7.f*81.f);
    const float w11 = 1.f/(7.f*121.f);
    const float w13 = 1.f/(7.f*169.f);
    const float w15 = 1.f/(7.f*225.f);

    auto ld4 = [&](const float* __restrict__ rowp, int c) -> float4 {
        if (c >= 0 && c <= W - 4) return *(const float4*)(rowp + c);
        float4 v;
        v.x = rowp[min(max(c    , 0), W - 1)];
        v.y = rowp[min(max(c + 1, 0), W - 1)];
        v.z = rowp[min(max(c + 2, 0), W - 1)];
        v.w = rowp[min(max(c + 3, 0), W - 1)];
        return v;
    };

    float4 mreg[GROUP];

    auto load_group = [&](int g) {
        if (t < NCHUNK) {
            const int rb = i0 - RAD + g * GROUP;
#pragma unroll
            for (int rr = 0; rr < GROUP; ++rr) {
                const int rc = min(max(rb + rr, 0), H - 1);
                mreg[rr] = ld4(x + (size_t)rc * W, c0 - 8 + 4 * t);
            }
        }
    };

    auto write_group = [&](int b) {
        if (t < NCHUNK) {
#pragma unroll
            for (int rr = 0; rr < GROUP; ++rr)
                *(float4*)&buf[b][rr][4 * t] = mreg[rr];
        }
    };

    // Pending outputs, group-relative: before group g, Pnd[p] accumulates
    // output row (i0 + 4g - 14 + p). All indices static: rr and Delta are
    // compile-time in the unrolled rr-loop; g stays RUNTIME (no unroll
    // needed for registers -- fixes round-3/4 scratch demotion).
    f32x2 Pnd[PEND];
#pragma unroll
    for (int q = 0; q < PEND; ++q) Pnd[q] = f32x2{0.f, 0.f};

    auto compute_group = [&](int b, int g) {
#pragma unroll
        for (int rr = 0; rr < GROUP; ++rr) {
            if (g * GROUP + rr < NSTAGE) {
                // q2[i] = row floats {2t+2i, 2t+2i+1}; covers [2t, 2t+17]
                const float* p = &buf[b][rr][2 * t];
                f32x2 q2[9];
#pragma unroll
                for (int i = 0; i < 9; ++i) q2[i] = *(const f32x2*)(p + 2 * i);

                // PR(a) = {row[2t+a], row[2t+a+1]}, a compile-time
                auto PR = [&](int a) -> f32x2 {
                    if ((a & 1) == 0) return q2[a / 2];
                    f32x2 r;
                    r.x = q2[a / 2].y;
                    r.y = q2[a / 2 + 1].x;
                    return r;
                };

                f32x2 s3  = PR(7) + PR(8) + PR(9);
                f32x2 s5  = s3  + PR(6) + PR(10);
                f32x2 s7  = s5  + PR(5) + PR(11);
                f32x2 s9  = s7  + PR(4) + PR(12);
                f32x2 s11 = s9  + PR(3) + PR(13);
                f32x2 s13 = s11 + PR(2) + PR(14);
                f32x2 s15 = s13 + PR(1) + PR(15);

                f32x2 c7 = f32x2{w15, w15} * s15;
                f32x2 c6 = c7 + f32x2{w13, w13} * s13;
                f32x2 c5 = c6 + f32x2{w11, w11} * s11;
                f32x2 c4 = c5 + f32x2{w9 , w9 } * s9;
                f32x2 c3 = c4 + f32x2{w7 , w7 } * s7;
                f32x2 c2 = c3 + f32x2{w5 , w5 } * s5;
                f32x2 c1 = c2 + f32x2{w3 , w3 } * s3;

                // scatter: Pnd[rr + 7 + Delta] += cum[|Delta|], all static
                Pnd[rr +  0] += c7; Pnd[rr +  1] += c6; Pnd[rr +  2] += c5;
                Pnd[rr +  3] += c4; Pnd[rr +  4] += c3; Pnd[rr +  5] += c2;
                Pnd[rr +  6] += c1; Pnd[rr +  7] += c1; Pnd[rr +  8] += c1;
                Pnd[rr +  9] += c2; Pnd[rr + 10] += c3; Pnd[rr + 11] += c4;
                Pnd[rr + 12] += c5; Pnd[rr + 13] += c6; Pnd[rr + 14] += c7;
            }
        }

        // emit the 4 completed output rows: o_ofs = 4g - 14 + p
#pragma unroll
        for (int p = 0; p < GROUP; ++p) {
            const int o_ofs = 4 * g - 14 + p;
            if (o_ofs >= 0 && o_ofs < SR) {
                const size_t bi = (size_t)(i0 + o_ofs) * W + c0 + 2 * t;
                f32x2 bm = *(const f32x2*)(base + bi);
                f32x2 ov = Pnd[p] * bm;
                *(f32x2*)(out + bi) = ov;
            }
        }

        // shift window by GROUP (static indices, ~4.5 ops/row amortized)
#pragma unroll
        for (int p = 0; p < PEND - GROUP; ++p) Pnd[p] = Pnd[p + GROUP];
#pragma unroll
        for (int p = PEND - GROUP; p < PEND; ++p) Pnd[p] = f32x2{0.f, 0.f};
    };

    load_group(0);
    write_group(0);
    __syncthreads();

    for (int g = 0; g < NG - 1; ++g) {          // runtime loop -- no unroll needed
        load_group(g + 1);           // issue next group's global loads early
        compute_group(g & 1, g);     // compute current group (hides latency)
        write_group((g + 1) & 1);    // land prefetched rows
        __syncthreads();
    }
    compute_group((NG - 1) & 1, NG - 1);
}

extern "C" void kernel_launch(void* const* d_in, const int* in_sizes, int n_in,
                              void* d_out, int out_size, void* d_ws, size_t ws_size,
                              hipStream_t stream) {
    const float* x    = (const float*)d_in[0];
    const float* base = (const float*)d_in[1];
    float* out        = (float*)d_out;

    dim3 grid(W / COLS, H / SR);   // (8, 128) = 1024 blocks
    multibox_kernel<<<grid, dim3(NT), 0, stream>>>(x, base, out);
}